// Round 6
// baseline (514.831 us; speedup 1.0000x reference)
//
#include <hip/hip_runtime.h>
#include <hip/hip_bf16.h>
#include <cstdint>

#define BB 8
#define CC 16
#define DD 32
#define HH 112
#define WW 112
#define TT 16        // D_OUT
#define HID 256
#define OUTN 128
#define INSZ 784     // C*7*7

__device__ __forceinline__ float bf16lo(uint32_t u) { return __uint_as_float(u << 16); }
__device__ __forceinline__ float bf16hi(uint32_t u) { return __uint_as_float(u & 0xffff0000u); }
__device__ __forceinline__ float bf16s(uint16_t u)  { return __uint_as_float(((uint32_t)u) << 16); }

__device__ __forceinline__ uint16_t f32_to_bf16_rne(float f) {
    uint32_t u = __float_as_uint(f);
    return (uint16_t)((u + 0x7fffu + ((u >> 16) & 1u)) >> 16);
}

// ---------------------------------------------------------------------------
// Dtype detector (PROVEN r2/r5): flag=1 -> float32 inputs, 0 -> bfloat16.
// ---------------------------------------------------------------------------
__global__ __launch_bounds__(256) void detect_kernel(const uint16_t* __restrict__ x,
                                                     int* __restrict__ flag) {
    __shared__ int cnt;
    if (threadIdx.x == 0) cnt = 0;
    __syncthreads();
    int local = 0;
    for (int i = threadIdx.x; i < 8192; i += 256) {
        uint32_t e = (x[i] >> 7) & 0xFFu;
        if (e == 0u || e >= 0x90u) local++;
    }
    atomicAdd(&cnt, local);
    __syncthreads();
    if (threadIdx.x == 0) *flag = (cnt > 400) ? 1 : 0;
}

// ---------------------------------------------------------------------------
// Pool (IDENTICAL to round-5 PASS): x -> seq (T,B,INSZ) f32, mean over 512.
// ---------------------------------------------------------------------------
__global__ __launch_bounds__(256) void pool_kernel(const void* __restrict__ xv,
                                                   float* __restrict__ seq,
                                                   const int* __restrict__ flag) {
    const int isf32 = *flag;
    int gid = blockIdx.x;                 // 2048 blocks
    int t = gid & 15, c = (gid >> 4) & 15, b = gid >> 8;
    long base = (long)(((b * CC + c) * DD) + t * 2) * (HH * WW);
    __shared__ float chunk[6272];
    int tid = threadIdx.x;
    float s = 0.0f;
    if (!isf32) {
        const uint4* p = reinterpret_cast<const uint4*>((const uint16_t*)xv + base);
        for (int m = tid; m < 3136; m += 256) {
            uint4 v = p[m];
            chunk[m] = bf16lo(v.x) + bf16hi(v.x) + bf16lo(v.y) + bf16hi(v.y)
                     + bf16lo(v.z) + bf16hi(v.z) + bf16lo(v.w) + bf16hi(v.w);
        }
        __syncthreads();
        if (tid < 49) {
            int h2 = tid / 7, w2 = tid - h2 * 7;
            #pragma unroll
            for (int d = 0; d < 2; d++)
                for (int hh = 0; hh < 16; hh++) {
                    int row = d * 1568 + (h2 * 16 + hh) * 14 + w2 * 2;
                    s += chunk[row] + chunk[row + 1];
                }
        }
    } else {
        const float4* p = reinterpret_cast<const float4*>((const float*)xv + base);
        for (int m = tid; m < 6272; m += 256) {
            float4 v = p[m];
            chunk[m] = v.x + v.y + v.z + v.w;
        }
        __syncthreads();
        if (tid < 49) {
            int h2 = tid / 7, w2 = tid - h2 * 7;
            #pragma unroll
            for (int d = 0; d < 2; d++)
                for (int hh = 0; hh < 16; hh++) {
                    int row = d * 3136 + (h2 * 16 + hh) * 28 + w2 * 4;
                    s += chunk[row] + chunk[row + 1] + chunk[row + 2] + chunk[row + 3];
                }
        }
    }
    if (tid < 49) {
        seq[(long)(t * BB + b) * INSZ + c * 49 + tid] = s * (1.0f / 512.0f);
    }
}

// ---------------------------------------------------------------------------
// W_ih -> f32 transposed wihT[k][768] (single full pack; ws is 822 MB).
// ---------------------------------------------------------------------------
__global__ __launch_bounds__(256) void pack_wih(const void* __restrict__ W,
                                                float* __restrict__ WT,
                                                const int* __restrict__ flag) {
    const int isf32 = *flag;
    int g = blockIdx.x * 256 + threadIdx.x;   // 602112 exactly
    int j = g / INSZ, k = g - j * INSZ;
    float v = isf32 ? ((const float*)W)[g] : bf16s(((const uint16_t*)W)[g]);
    WT[(long)k * 768 + j] = v;
}

// ---------------------------------------------------------------------------
// W_hh -> packed bf16 pairs, transposed: whhP[kk][768], kk in [0,128).
// bf16 input: exact copy-transpose (the u32 IS the pair). f32: rne-quantize.
// ---------------------------------------------------------------------------
__global__ __launch_bounds__(256) void pack_whh(const void* __restrict__ W,
                                                uint32_t* __restrict__ WP,
                                                const int* __restrict__ flag) {
    const int isf32 = *flag;
    int g = blockIdx.x * 256 + threadIdx.x;   // 98304 exactly
    int j = g >> 7, kk = g & 127;
    uint32_t u;
    if (isf32) {
        float2 v = ((const float2*)W)[g];     // W[j][2kk], W[j][2kk+1]
        u = (uint32_t)f32_to_bf16_rne(v.x) | ((uint32_t)f32_to_bf16_rne(v.y) << 16);
    } else {
        u = ((const uint32_t*)W)[g];
    }
    WP[kk * 768 + j] = u;
}

// ---------------------------------------------------------------------------
// gi[tb][j] = b_ih[j] + dot(seq[tb,:], W_ih[j,:]).
// Grid 96 = 3 j-groups x 32 tb-groups (4 tb each). 256 threads = 1 j each,
// 4 tb register accumulators; seq tile transposed in LDS (float4 per k).
// ---------------------------------------------------------------------------
__global__ __launch_bounds__(256) void gi_kernel(const float* __restrict__ seq,
                                                 const float* __restrict__ wihT,
                                                 const void* __restrict__ bih,
                                                 float* __restrict__ gi,
                                                 const int* __restrict__ flag) {
    const int isf32 = *flag;
    int jg = blockIdx.x % 3, tbg = blockIdx.x / 3;
    int tb0 = tbg * 4;
    int j = jg * 256 + threadIdx.x;
    __shared__ __align__(16) float s_in[INSZ * 4];   // s_in[k*4 + i]
    const float* sbase = seq + (long)tb0 * INSZ;
    for (int idx = threadIdx.x; idx < INSZ * 4; idx += 256) {
        int i = idx / INSZ, k = idx - i * INSZ;      // coalesced reads
        s_in[k * 4 + i] = sbase[idx];
    }
    __syncthreads();
    float bv = isf32 ? ((const float*)bih)[j] : bf16s(((const uint16_t*)bih)[j]);
    float a0 = bv, a1 = bv, a2 = bv, a3 = bv;
    const float* wp = wihT + j;
    const float4* s4 = reinterpret_cast<const float4*>(s_in);
    #pragma unroll 8
    for (int k = 0; k < INSZ; k++) {
        float w = wp[(long)k * 768];                 // coalesced across lanes
        float4 sv = s4[k];                           // LDS broadcast
        a0 += w * sv.x; a1 += w * sv.y; a2 += w * sv.z; a3 += w * sv.w;
    }
    gi[(long)(tb0 + 0) * 768 + j] = a0;
    gi[(long)(tb0 + 1) * 768 + j] = a1;
    gi[(long)(tb0 + 2) * 768 + j] = a2;
    gi[(long)(tb0 + 3) * 768 + j] = a3;
}

// ---------------------------------------------------------------------------
// Sequential GRU, register-resident weights: one block per batch, 768 thr.
// Thread j holds row j of W_hh as 128 packed-bf16 u32 in VGPRs (coalesced
// one-time load). 16 steps of pure FMA + LDS-broadcast h. j<256 gates;
// j<128 final linear (one-time, reads W_out directly).
// ---------------------------------------------------------------------------
__global__ __launch_bounds__(768, 3) void gru_kernel(const float* __restrict__ gi,
                                                     const uint32_t* __restrict__ whhP,
                                                     const void* __restrict__ bhh,
                                                     const void* __restrict__ Wout,
                                                     const void* __restrict__ bout,
                                                     void* __restrict__ out,
                                                     const int* __restrict__ flag) {
    const int isf32 = *flag;
    int b = blockIdx.x;
    int j = threadIdx.x;
    __shared__ __align__(16) float h_s[HID];
    __shared__ __align__(16) float g_s[768];
    if (j < HID) h_s[j] = 0.0f;
    float bh = isf32 ? ((const float*)bhh)[j] : bf16s(((const uint16_t*)bhh)[j]);

    uint32_t w[128];
    #pragma unroll
    for (int kk = 0; kk < 128; kk++) w[kk] = whhP[kk * 768 + j];  // coalesced

    __syncthreads();
    #pragma unroll 1
    for (int t = 0; t < TT; t++) {
        float acc = bh;
        const float2* h2p = reinterpret_cast<const float2*>(h_s);
        #pragma unroll
        for (int kk = 0; kk < 128; kk++) {
            float2 hv = h2p[kk];                     // LDS broadcast
            uint32_t u = w[kk];                      // register
            acc += bf16lo(u) * hv.x + bf16hi(u) * hv.y;
        }
        g_s[j] = acc;
        __syncthreads();                             // g ready; dots done with h_s
        if (j < HID) {
            const float* gp = gi + (long)(t * BB + b) * 768;
            float r = 1.0f / (1.0f + __expf(-(gp[j]       + g_s[j])));
            float z = 1.0f / (1.0f + __expf(-(gp[j + 256] + g_s[j + 256])));
            float npre = gp[j + 512] + r * g_s[j + 512];
            float n = 2.0f / (1.0f + __expf(-2.0f * npre)) - 1.0f;  // tanh
            h_s[j] = (1.0f - z) * n + z * h_s[j];
        }
        __syncthreads();                             // h ready for next step
    }
    if (j < OUTN) {
        float acc = isf32 ? ((const float*)bout)[j] : bf16s(((const uint16_t*)bout)[j]);
        if (!isf32) {
            const uint4* wo = reinterpret_cast<const uint4*>((const uint16_t*)Wout + (long)j * HID);
            #pragma unroll
            for (int k = 0; k < 32; k++) {
                uint4 v = wo[k];
                const float* hp2 = &h_s[k * 8];
                acc += bf16lo(v.x) * hp2[0] + bf16hi(v.x) * hp2[1]
                     + bf16lo(v.y) * hp2[2] + bf16hi(v.y) * hp2[3]
                     + bf16lo(v.z) * hp2[4] + bf16hi(v.z) * hp2[5]
                     + bf16lo(v.w) * hp2[6] + bf16hi(v.w) * hp2[7];
            }
            ((uint16_t*)out)[b * OUTN + j] = f32_to_bf16_rne(acc);
        } else {
            const float4* wo = reinterpret_cast<const float4*>((const float*)Wout + (long)j * HID);
            #pragma unroll
            for (int k = 0; k < 64; k++) {
                float4 v = wo[k];
                const float* hp2 = &h_s[k * 4];
                acc += v.x * hp2[0] + v.y * hp2[1] + v.z * hp2[2] + v.w * hp2[3];
            }
            ((float*)out)[b * OUTN + j] = acc;
        }
    }
}

extern "C" void kernel_launch(void* const* d_in, const int* in_sizes, int n_in,
                              void* d_out, int out_size, void* d_ws, size_t ws_size,
                              hipStream_t stream) {
    const void* x    = d_in[0];  // 8*16*32*112*112
    const void* Wih  = d_in[1];  // 768*784
    const void* Whh  = d_in[2];  // 768*256
    const void* bih  = d_in[3];  // 768
    const void* bhh  = d_in[4];  // 768
    const void* Wout = d_in[5];  // 128*256
    const void* bout = d_in[6];  // 128

    // ws_size ~822 MB (measured via harness fill) — use generous fixed layout.
    char* ws = (char*)d_ws;
    float*    seq  = (float*)ws;                  // 401408 B
    float*    gi   = (float*)(ws + 401408);       // 393216 B
    float*    wihT = (float*)(ws + 1048576);      // 2408448 B  [784][768] f32
    uint32_t* whhP = (uint32_t*)(ws + 4194304);   // 393216 B   [128][768] u32
    int*     flagp = (int*)(ws + 8388608);

    detect_kernel<<<1, 256, 0, stream>>>((const uint16_t*)x, flagp);
    pool_kernel<<<2048, 256, 0, stream>>>(x, seq, flagp);
    pack_wih<<<2352, 256, 0, stream>>>(Wih, wihT, flagp);
    pack_whh<<<384, 256, 0, stream>>>(Whh, whhP, flagp);
    gi_kernel<<<96, 256, 0, stream>>>(seq, wihT, bih, gi, flagp);
    gru_kernel<<<8, 768, 0, stream>>>(gi, whhP, bhh, Wout, bout, d_out, flagp);
}